// Round 12
// baseline (172.080 us; speedup 1.0000x reference)
//
#include <hip/hip_runtime.h>
#include <math.h>

#define DIM 768
#define HEADS 16
#define DKH 48          // head dim
#define SEQ 2048
#define BATCH 2
#define M_TOT (BATCH*SEQ)                  // 4096
#define PART  (32*2048*48)                 // elems per split-K O partial
#define QTOT  (32*2048)                    // total (bh, s) rows
#define KSPL  3                            // split-K ways: 704/704/640 keys
#define KSPLIT0 704                        // 11 iters of 64 (z=0,1); z=2: 10

typedef __bf16 v8bf16 __attribute__((ext_vector_type(8)));
typedef __bf16 v4bf16 __attribute__((ext_vector_type(4)));
typedef float  v4f32  __attribute__((ext_vector_type(4)));

#define GLDS(g, l) __builtin_amdgcn_global_load_lds( \
    (const __attribute__((address_space(1))) void*)(g), \
    (__attribute__((address_space(3))) void*)(l), 16, 0, 0)

// ---------------------------------------------------------------------------
// fp32 -> bf16 conversion of x and the 4 weight matrices.
// ---------------------------------------------------------------------------
#define XN4 786432      // 4096*768/4
#define WN4 147456      // 768*768/4
__global__ __launch_bounds__(256) void convert_kernel(
    const float* __restrict__ x,
    const float* __restrict__ Wq, const float* __restrict__ Wk,
    const float* __restrict__ Wv, const float* __restrict__ Wo,
    __bf16* __restrict__ xb,
    __bf16* __restrict__ Wqb, __bf16* __restrict__ Wkb,
    __bf16* __restrict__ Wvb, __bf16* __restrict__ Wob)
{
    int f = blockIdx.x * 256 + threadIdx.x;
    const float* src; __bf16* dst;
    if (f < XN4)                { src = x;  dst = xb; }
    else if (f < XN4 + WN4)     { src = Wq; dst = Wqb; f -= XN4; }
    else if (f < XN4 + 2*WN4)   { src = Wk; dst = Wkb; f -= XN4 + WN4; }
    else if (f < XN4 + 3*WN4)   { src = Wv; dst = Wvb; f -= XN4 + 2*WN4; }
    else                        { src = Wo; dst = Wob; f -= XN4 + 3*WN4; }
    float4 v = ((const float4*)src)[f];
    v4bf16 b;
    b[0] = (__bf16)v.x; b[1] = (__bf16)v.y;
    b[2] = (__bf16)v.z; b[3] = (__bf16)v.w;
    *(v4bf16*)&dst[(size_t)f * 4] = b;
}

// ---------------------------------------------------------------------------
// QKV MFMA GEMM: C = A @ W^T, A[4096][768] bf16, W[768][768] bf16.
// 128x96 tile, BK=64 (12 k-iters): linear LDS dest + XOR-preswizzled GLOBAL
// source + XOR on read (col8 ^ (row&7)) — rule #21 both-sides swizzle.
// GRID dim3(32, 8, 3), m on x: the 24 blocks sharing one 192 KB A-slice
// co-locate per XCD L2 (R11: part of the −7 us GEMM win).
// z=0: Q (scaled by log2e/sqrt(48)) -> [B,H,S,dk]. z=1: K -> [B,H,S,dk].
// z=2: V -> TRANSPOSED [B,H,dk,S] via b64 stores.
// ---------------------------------------------------------------------------
__global__ __launch_bounds__(256) void qkv_mfma_kernel(
    const __bf16* __restrict__ xb,
    const __bf16* __restrict__ Wqb, const float* __restrict__ bq,
    const __bf16* __restrict__ Wkb, const float* __restrict__ bk,
    const __bf16* __restrict__ Wvb, const float* __restrict__ bv,
    __bf16* __restrict__ Qo, __bf16* __restrict__ Ko, __bf16* __restrict__ Vo)
{
    __shared__ __bf16 As[128 * 64];
    __shared__ __bf16 Bs[128 * 64];

    const int z = blockIdx.z;
    const __bf16* W   = (z == 0) ? Wqb : ((z == 1) ? Wkb : Wvb);
    const float* bias = (z == 0) ? bq  : ((z == 1) ? bk  : bv);
    __bf16* out       = (z == 0) ? Qo  : ((z == 1) ? Ko  : Vo);

    const int m0 = blockIdx.x * 128;         // m on x: A-sharers co-locate
    const int n0 = blockIdx.y * 96;
    const int t  = threadIdx.x;
    const int w    = t >> 6;
    const int lane = t & 63;
    const int low4 = lane & 15;
    const int quad = lane >> 4;
    const int wm = w >> 1, wn = w & 1;
    const int rswz = (low4 & 7) * 8;         // read-side XOR (elems)

    v4f32 acc[4][3];
#pragma unroll
    for (int i = 0; i < 4; ++i)
#pragma unroll
        for (int j = 0; j < 3; ++j)
            acc[i][j] = (v4f32){0.f, 0.f, 0.f, 0.f};

    for (int k0 = 0; k0 < DIM; k0 += 64) {
        // stage 128x64 A and B tiles: 8 GLDS/thread, source-preswizzled
#pragma unroll
        for (int k = 0; k < 4; ++k) {
            const int c = t + k * 256;                 // chunk 0..1023
            const int row = c >> 3, col8 = c & 7;
            GLDS(xb + (size_t)(m0 + row) * DIM + k0 + ((col8 ^ (row & 7)) * 8),
                 &As[c * 8]);
        }
#pragma unroll
        for (int k = 0; k < 4; ++k) {
            const int c = t + k * 256;
            const int row = c >> 3, col8 = c & 7;
            GLDS(W + (size_t)(n0 + row) * DIM + k0 + ((col8 ^ (row & 7)) * 8),
                 &Bs[c * 8]);
        }
        __syncthreads();

#pragma unroll
        for (int kk = 0; kk < 2; ++kk) {
            v8bf16 af[4], bf[3];
            const int cbase = (kk * 32 + quad * 8) ^ rswz;
#pragma unroll
            for (int i = 0; i < 4; ++i)
                af[i] = *(const v8bf16*)&As[(wm * 64 + i * 16 + low4) * 64 + cbase];
#pragma unroll
            for (int j = 0; j < 3; ++j)
                bf[j] = *(const v8bf16*)&Bs[(wn * 48 + j * 16 + low4) * 64 + cbase];
#pragma unroll
            for (int i = 0; i < 4; ++i)
#pragma unroll
                for (int j = 0; j < 3; ++j)
                    acc[i][j] = __builtin_amdgcn_mfma_f32_16x16x32_bf16(af[i], bf[j], acc[i][j], 0, 0, 0);
        }
        __syncthreads();
    }

    // scale = log2(e)/sqrt(48), folded into Q so attention can use exp2
    const float scale = 0.2082351055f;
#pragma unroll
    for (int j = 0; j < 3; ++j) {
        const int e = n0 + wn * 48 + j * 16 + low4;
        const float b = bias[e];
        const int h = e / DKH;
        const int d = e - h * DKH;
        if (z == 2) {
            // V^T: 4 consecutive s per lane -> one b64 store
#pragma unroll
            for (int i = 0; i < 4; ++i) {
                const int m_base = m0 + wm * 64 + i * 16 + quad * 4;
                const int bb = m_base >> 11;
                const int s  = m_base & (SEQ - 1);
                v4bf16 pk;
#pragma unroll
                for (int r = 0; r < 4; ++r) pk[r] = (__bf16)(acc[i][j][r] + b);
                *(v4bf16*)&out[((size_t)(bb * HEADS + h) * DKH + d) * SEQ + s] = pk;
            }
        } else {
#pragma unroll
            for (int i = 0; i < 4; ++i) {
#pragma unroll
                for (int r = 0; r < 4; ++r) {
                    const int m  = m0 + wm * 64 + i * 16 + quad * 4 + r;
                    const int bb = m >> 11;
                    const int s  = m & (SEQ - 1);
                    float v = acc[i][j][r] + b;
                    if (z == 0) v *= scale;
                    out[((size_t)(bb * HEADS + h) * SEQ + s) * DKH + d] = (__bf16)v;
                }
            }
        }
    }
}

// ---------------------------------------------------------------------------
// Output projection: out[m][e] = ctx[m][:] . Wo[e][:] + bo[e], fp32 out.
// 64x96 tile, BK=64, same source-preswizzle scheme as qkv (12 k-iters).
// GRID dim3(64, 8), m on x: CTX-slice sharers co-locate per XCD L2.
// ---------------------------------------------------------------------------
__global__ __launch_bounds__(256) void out_mfma_kernel(
    const __bf16* __restrict__ ctx, const __bf16* __restrict__ Wob,
    const float* __restrict__ bo, float* __restrict__ outp)
{
    __shared__ __bf16 As[64 * 64];
    __shared__ __bf16 Bs[128 * 64];

    const int m0 = blockIdx.x * 64;          // m on x: CTX-sharers co-locate
    const int n0 = blockIdx.y * 96;
    const int t  = threadIdx.x;
    const int w    = t >> 6;
    const int lane = t & 63;
    const int low4 = lane & 15;
    const int quad = lane >> 4;
    const int wm = w >> 1, wn = w & 1;
    const int rswz = (low4 & 7) * 8;

    v4f32 acc[2][3];
#pragma unroll
    for (int i = 0; i < 2; ++i)
#pragma unroll
        for (int j = 0; j < 3; ++j)
            acc[i][j] = (v4f32){0.f, 0.f, 0.f, 0.f};

    for (int k0 = 0; k0 < DIM; k0 += 64) {
#pragma unroll
        for (int k = 0; k < 2; ++k) {
            const int c = t + k * 256;                 // As chunk 0..511
            const int row = c >> 3, col8 = c & 7;
            GLDS(ctx + (size_t)(m0 + row) * DIM + k0 + ((col8 ^ (row & 7)) * 8),
                 &As[c * 8]);
        }
#pragma unroll
        for (int k = 0; k < 4; ++k) {
            const int c = t + k * 256;                 // Bs chunk 0..1023
            const int row = c >> 3, col8 = c & 7;
            GLDS(Wob + (size_t)(n0 + row) * DIM + k0 + ((col8 ^ (row & 7)) * 8),
                 &Bs[c * 8]);
        }
        __syncthreads();

#pragma unroll
        for (int kk = 0; kk < 2; ++kk) {
            v8bf16 af[2], bf[3];
            const int cbase = (kk * 32 + quad * 8) ^ rswz;
#pragma unroll
            for (int i = 0; i < 2; ++i)
                af[i] = *(const v8bf16*)&As[(wm * 32 + i * 16 + low4) * 64 + cbase];
#pragma unroll
            for (int j = 0; j < 3; ++j)
                bf[j] = *(const v8bf16*)&Bs[(wn * 48 + j * 16 + low4) * 64 + cbase];
#pragma unroll
            for (int i = 0; i < 2; ++i)
#pragma unroll
                for (int j = 0; j < 3; ++j)
                    acc[i][j] = __builtin_amdgcn_mfma_f32_16x16x32_bf16(af[i], bf[j], acc[i][j], 0, 0, 0);
        }
        __syncthreads();
    }

#pragma unroll
    for (int j = 0; j < 3; ++j) {
        const int e = n0 + wn * 48 + j * 16 + low4;
        const float b = bo[e];
#pragma unroll
        for (int i = 0; i < 2; ++i) {
#pragma unroll
            for (int r = 0; r < 4; ++r) {
                const int m = m0 + wm * 32 + i * 16 + quad * 4 + r;
                outp[(size_t)m * DIM + e] = acc[i][j][r] + b;
            }
        }
    }
}

// ---------------------------------------------------------------------------
// MFMA flash attention, SPLIT-K x3 (z = key third: 704/704/640 keys),
// no-max softmax (exact: shift-invariant + bounded scores; Q pre-scaled by
// log2e/sqrt(48) -> exp2). 8 waves x 32 queries/wave.
// THIS ROUND (T2): all LDS tiles re-pitched 72 -> 64 elems (8 x 16B chunks,
// row*8 ≡ 0 mod 8 bank-chunks) + XOR chunk swizzle chunk ^= row&7 on BOTH
// writes and reads (rule #21). Old pitch 36 dw ≡ 4 mod 32 clustered every
// b128 read's start bank on 8 values x 8 lanes -> 7.5M conflict-cycles
// (~12 us/dispatch). New start bank-chunk = quad ^ (low4&7): uniform, only
// the free 2-way (low4 vs low4+8). LDS 53248 -> 47104 B (still 3 blk/CU).
// GRID dim3(96, 8): K/V-third sharers co-locate per XCD (FETCH 55->17 MB).
// Swapped QK^T: S^T = mfma(K,Q) -> packed b64 P-stores.
// NO 2nd launch_bounds arg (R1/R8 spill rule). No setprio (R5 regression).
// Outputs UNNORMALIZED O (bf16) + l (fp32); merge kernel divides.
// ---------------------------------------------------------------------------
#define SWZ(r, e) (((((e) >> 3) ^ ((r) & 7)) << 3) | ((e) & 7))

__global__ __launch_bounds__(512) void attention_kernel(
    const __bf16* __restrict__ Q, const __bf16* __restrict__ K,
    const __bf16* __restrict__ Vt_g, __bf16* __restrict__ Opart,
    float* __restrict__ lbuf)
{
    __shared__ __bf16 PQ[256 * 64];  // Qs during init, then Ps [query][key]
    __shared__ __bf16 Ks[64 * 64];   // [key][dk padded 48->64]
    __shared__ __bf16 Vt[48 * 64];   // [d][key]

    const int grp  = blockIdx.x;            // 0..95: (bh, key-third) group
    const int bh   = grp / 3;
    const int z    = grp - bh * 3;
    const int q0   = blockIdx.y * 256;
    const int kh0  = z * KSPLIT0;                       // key third start
    const int khend = (z == 2) ? SEQ : kh0 + KSPLIT0;
    const int t    = threadIdx.x;
    const int w    = t >> 6;        // 0..7
    const int lane = t & 63;
    const int low4 = lane & 15;
    const int quad = lane >> 4;

    const __bf16* Qbh = Q    + (size_t)bh * SEQ * DKH;
    const __bf16* Kbh = K    + (size_t)bh * SEQ * DKH;
    const __bf16* Vbh = Vt_g + (size_t)bh * SEQ * DKH;  // [d][s]

    // ---- stage Q tile (256 x 48, pre-scaled, swizzled); zero pad 48..63 ----
    {
        const int row = t >> 1;
        const int c0  = (t & 1) * 24;
        const __bf16* src = &Qbh[(size_t)(q0 + row) * DKH + c0];
#pragma unroll
        for (int jj = 0; jj < 6; ++jj)
            *(v4bf16*)&PQ[row * 64 + SWZ(row, c0 + jj * 4)] = *(const v4bf16*)&src[jj * 4];
        v4bf16 zz = {(__bf16)0.f, (__bf16)0.f, (__bf16)0.f, (__bf16)0.f};
        const int pz = 48 + (t & 1) * 8;
        *(v4bf16*)&PQ[row * 64 + SWZ(row, pz)]     = zz;
        *(v4bf16*)&PQ[row * 64 + SWZ(row, pz + 4)] = zz;
        if (t < 256) {
            const int kr = t >> 2, ke = 48 + (t & 3) * 4;
            *(v4bf16*)&Ks[kr * 64 + SWZ(kr, ke)] = zz;   // Ks pad cols 48..63
        }
    }
    __syncthreads();

    // Q A-fragments: wave w owns query rows w*32 .. w*32+31 (tiles i=0,1)
    v8bf16 aq[2][2];
#pragma unroll
    for (int i = 0; i < 2; ++i)
#pragma unroll
        for (int ks = 0; ks < 2; ++ks) {
            const int qr = w * 32 + i * 16 + low4;
            aq[i][ks] = *(const v8bf16*)&PQ[qr * 64 + SWZ(qr, ks * 32 + quad * 8)];
        }

    // ones B-fragment for l row-sums
    v8bf16 ones;
#pragma unroll
    for (int jj = 0; jj < 8; ++jj) ones[jj] = (__bf16)1.0f;

    v4f32 lacc[2];
    v4f32 oacc[2][3];
#pragma unroll
    for (int i = 0; i < 2; ++i) {
        lacc[i] = (v4f32){0.f, 0.f, 0.f, 0.f};
#pragma unroll
        for (int dt = 0; dt < 3; ++dt)
            oacc[i][dt] = (v4f32){0.f, 0.f, 0.f, 0.f};
    }

    // staging coords: waves 0-3 -> K (64 rows), waves 4-6 -> V^T (48 rows)
    const int krow = t >> 2;              // K: key row 0..63   (t < 256)
    const int kc0  = (t & 3) * 12;        // K: dk chunk
    const int vrow = (t >> 2) - 64;       // V^T: d row 0..47   (256 <= t < 448)
    const int vc0  = (t & 3) * 16;        // V^T: key chunk

    // ---- prefetch tile 0 into registers ----
    v4bf16 kreg[3];
    v8bf16 vreg0, vreg1;
    if (t < 256) {
        const __bf16* sk = &Kbh[(size_t)(kh0 + krow) * DKH + kc0];
        kreg[0] = *(const v4bf16*)&sk[0];
        kreg[1] = *(const v4bf16*)&sk[4];
        kreg[2] = *(const v4bf16*)&sk[8];
    } else if (t < 448) {
        const __bf16* sv = &Vbh[(size_t)vrow * SEQ + kh0 + vc0];
        vreg0 = *(const v8bf16*)&sv[0];
        vreg1 = *(const v8bf16*)&sv[8];
    }

    for (int k0 = kh0; k0 < khend; k0 += 64) {
        __syncthreads();   // prior LDS reads done (and Q frag reads, iter 0)

        // ---- write prefetched tile to LDS (swizzled) ----
        if (t < 256) {
#pragma unroll
            for (int jj = 0; jj < 3; ++jj)
                *(v4bf16*)&Ks[krow * 64 + SWZ(krow, kc0 + jj * 4)] = kreg[jj];
        } else if (t < 448) {
            *(v8bf16*)&Vt[vrow * 64 + SWZ(vrow, vc0)]     = vreg0;
            *(v8bf16*)&Vt[vrow * 64 + SWZ(vrow, vc0 + 8)] = vreg1;
        }

        // ---- issue prefetch for next tile (overlaps compute below) ----
        if (k0 + 64 < khend) {
            if (t < 256) {
                const __bf16* sk = &Kbh[(size_t)(k0 + 64 + krow) * DKH + kc0];
                kreg[0] = *(const v4bf16*)&sk[0];
                kreg[1] = *(const v4bf16*)&sk[4];
                kreg[2] = *(const v4bf16*)&sk[8];
            } else if (t < 448) {
                const __bf16* sv = &Vbh[(size_t)vrow * SEQ + (k0 + 64) + vc0];
                vreg0 = *(const v8bf16*)&sv[0];
                vreg1 = *(const v8bf16*)&sv[8];
            }
        }
        __syncthreads();

        // ---- K B-fragments (shared across both query tiles) ----
        v8bf16 bk0[4], bk1[4];
#pragma unroll
        for (int tn = 0; tn < 4; ++tn) {
            const int kr = tn * 16 + low4;
            bk0[tn] = *(const v8bf16*)&Ks[kr * 64 + SWZ(kr, quad * 8)];
            bk1[tn] = *(const v8bf16*)&Ks[kr * 64 + SWZ(kr, 32 + quad * 8)];
        }

        // ---- S^T = K Q^T (swapped), p = exp2(s), packed b64 P-store ----
        // lane: query = low4 (C col), keys = tn*16 + quad*4 + r (C row)
#pragma unroll
        for (int i = 0; i < 2; ++i) {
            v4f32 sacc[4];
#pragma unroll
            for (int tn = 0; tn < 4; ++tn) {
                v4f32 c = {0.f, 0.f, 0.f, 0.f};
                c = __builtin_amdgcn_mfma_f32_16x16x32_bf16(bk0[tn], aq[i][0], c, 0, 0, 0);
                c = __builtin_amdgcn_mfma_f32_16x16x32_bf16(bk1[tn], aq[i][1], c, 0, 0, 0);
                sacc[tn] = c;
            }
            const int qr = w * 32 + i * 16 + low4;
#pragma unroll
            for (int tn = 0; tn < 4; ++tn) {
                v4bf16 pk;
#pragma unroll
                for (int r = 0; r < 4; ++r)
                    pk[r] = (__bf16)__builtin_amdgcn_exp2f(sacc[tn][r]);
                *(v4bf16*)&PQ[qr * 64 + SWZ(qr, tn * 16 + quad * 4)] = pk;
            }
        }

        // ---- O += P @ V; l += P @ ones ----
        v8bf16 bv0[3], bv1[3];
#pragma unroll
        for (int dt = 0; dt < 3; ++dt) {
            const int vr = dt * 16 + low4;
            bv0[dt] = *(const v8bf16*)&Vt[vr * 64 + SWZ(vr, quad * 8)];
            bv1[dt] = *(const v8bf16*)&Vt[vr * 64 + SWZ(vr, 32 + quad * 8)];
        }
#pragma unroll
        for (int i = 0; i < 2; ++i) {
            const int qr = w * 32 + i * 16 + low4;
            v8bf16 ap0 = *(const v8bf16*)&PQ[qr * 64 + SWZ(qr, quad * 8)];
            v8bf16 ap1 = *(const v8bf16*)&PQ[qr * 64 + SWZ(qr, 32 + quad * 8)];
#pragma unroll
            for (int dt = 0; dt < 3; ++dt) {
                oacc[i][dt] = __builtin_amdgcn_mfma_f32_16x16x32_bf16(ap0, bv0[dt], oacc[i][dt], 0, 0, 0);
                oacc[i][dt] = __builtin_amdgcn_mfma_f32_16x16x32_bf16(ap1, bv1[dt], oacc[i][dt], 0, 0, 0);
            }
            lacc[i] = __builtin_amdgcn_mfma_f32_16x16x32_bf16(ap0, ones, lacc[i], 0, 0, 0);
            lacc[i] = __builtin_amdgcn_mfma_f32_16x16x32_bf16(ap1, ones, lacc[i], 0, 0, 0);
        }
    }

    // ---- write unnormalized O partial (bf16) + l (fp32) ----
    const int kh = z;
#pragma unroll
    for (int i = 0; i < 2; ++i) {
#pragma unroll
        for (int r = 0; r < 4; ++r) {
            const int s  = q0 + w * 32 + i * 16 + quad * 4 + r;
            const int qg = bh * SEQ + s;
            __bf16* dst = Opart + (size_t)kh * PART + (size_t)qg * 48;
#pragma unroll
            for (int dt = 0; dt < 3; ++dt)
                dst[dt * 16 + low4] = (__bf16)oacc[i][dt][r];
            if (low4 == 0)
                lbuf[kh * QTOT + qg] = lacc[i][r];
        }
    }
}

// ---------------------------------------------------------------------------
// Merge split-K partials: ctx = sum(Oz) / sum(lz), bf16 out [B,S,768].
// ---------------------------------------------------------------------------
__global__ __launch_bounds__(256) void merge_kernel(
    const __bf16* __restrict__ Opart, const float* __restrict__ lbuf,
    __bf16* __restrict__ ctx)
{
    const int f  = (blockIdx.x * 256 + threadIdx.x) * 8;  // < 32*2048*48
    const int q  = f / 48;          // bh*2048 + s
    const int d0 = f - q * 48;
    v8bf16 a0 = *(const v8bf16*)&Opart[f];
    v8bf16 a1 = *(const v8bf16*)&Opart[(size_t)PART + f];
    v8bf16 a2 = *(const v8bf16*)&Opart[(size_t)2 * PART + f];
    const float inv = 1.0f / (lbuf[q] + lbuf[QTOT + q] + lbuf[2 * QTOT + q]);
    const int bh = q >> 11, s = q & (SEQ - 1);
    const int h = bh & (HEADS - 1), bb = bh >> 4;
    __bf16* dst = ctx + ((size_t)(bb * SEQ + s) * DIM) + h * DKH + d0;
    v8bf16 o;
#pragma unroll
    for (int j = 0; j < 8; ++j)
        o[j] = (__bf16)((((float)a0[j] + (float)a1[j]) + (float)a2[j]) * inv);
    *(v8bf16*)dst = o;
}

// ---------------------------------------------------------------------------
extern "C" void kernel_launch(void* const* d_in, const int* in_sizes, int n_in,
                              void* d_out, int out_size, void* d_ws, size_t ws_size,
                              hipStream_t stream) {
    const float* x  = (const float*)d_in[0];
    const float* Wq = (const float*)d_in[1];
    const float* bq = (const float*)d_in[2];
    const float* Wk = (const float*)d_in[3];
    const float* bk = (const float*)d_in[4];
    const float* Wv = (const float*)d_in[5];
    const float* bv = (const float*)d_in[6];
    const float* Wo = (const float*)d_in[7];
    const float* bo = (const float*)d_in[8];
    float* out = (float*)d_out;

    char* ws = (char*)d_ws;
    const size_t XB  = (size_t)M_TOT * DIM * 2;    // 6291456
    const size_t WBP = (size_t)800 * DIM * 2;      // 1228800 (768 rows + 32 pad)

    // Layout (peak ~46 MB). Opart/lbuf overlay the xb + Wq/Wk/Wv region,
    // which is dead once the QKV GEMM has run (kernels are stream-ordered).
    __bf16* Wob = (__bf16*)(ws);                       // lives until out_mfma
    __bf16* CTX = (__bf16*)(ws + WBP);
    __bf16* Qb  = (__bf16*)(ws + WBP + XB);
    __bf16* Kb  = (__bf16*)(ws + WBP + 2 * XB);
    __bf16* Vb  = (__bf16*)(ws + WBP + 3 * XB);        // [B,H,dk,S]
    __bf16* xb  = (__bf16*)(ws + WBP + 4 * XB);
    __bf16* Wqb = (__bf16*)(ws + WBP + 5 * XB);
    __bf16* Wkb = (__bf16*)(ws + WBP + 5 * XB + WBP);
    __bf16* Wvb = (__bf16*)(ws + WBP + 5 * XB + 2 * WBP);
    __bf16* Opart = (__bf16*)(ws + WBP + 4 * XB);                 // 3*PART bf16
    float*  lbuf  = (float*)(ws + WBP + 4 * XB + (size_t)KSPL * PART * 2);

    // 0) fp32 -> bf16 conversion of x and weights
    convert_kernel<<<dim3((XN4 + 4 * WN4) / 256), 256, 0, stream>>>(
        x, Wq, Wk, Wv, Wo, xb, Wqb, Wkb, Wvb, Wob);

    // 1) QKV projections (MFMA): grid (32 m, 8 n, 3 z) = 768 blocks,
    //    m on x so the 24 A-slice sharers co-locate per XCD L2
    qkv_mfma_kernel<<<dim3(32, 8, 3), 256, 0, stream>>>(
        xb, Wqb, bq, Wkb, bk, Wvb, bv, Qb, Kb, Vb);

    // 2) attention split-K: grid (96 groups = bh*3+z, 8 q-tiles) = 768 blocks
    //    = exactly 3 blocks/CU; XCD-aware: K/V sharers co-located per XCD L2
    attention_kernel<<<dim3(96, 8), 512, 0, stream>>>(Qb, Kb, Vb, Opart, lbuf);

    // 2b) merge partials: 32*2048*48/8/256 = 1536 blocks
    merge_kernel<<<dim3(1536), 256, 0, stream>>>(Opart, lbuf, CTX);

    // 3) output projection (MFMA): grid (64 m, 8 n) = 512 blocks,
    //    m on x so the 8 CTX-slice sharers co-locate per XCD L2
    out_mfma_kernel<<<dim3(64, 8), 256, 0, stream>>>(CTX, Wob, bo, out);
}

// Round 13
// 164.627 us; speedup vs baseline: 1.0453x; 1.0453x over previous
//
#include <hip/hip_runtime.h>
#include <math.h>

#define DIM 768
#define HEADS 16
#define DKH 48          // head dim
#define SEQ 2048
#define BATCH 2
#define M_TOT (BATCH*SEQ)                  // 4096
#define PART  (32*2048*48)                 // elems per split-K O partial
#define QTOT  (32*2048)                    // total (bh, s) rows
#define KSPL  3                            // split-K ways: 704/704/640 keys
#define KSPLIT0 704                        // 11 iters of 64 (z=0,1); z=2: 10

typedef __bf16 v8bf16 __attribute__((ext_vector_type(8)));
typedef __bf16 v4bf16 __attribute__((ext_vector_type(4)));
typedef float  v4f32  __attribute__((ext_vector_type(4)));

#define GLDS(g, l) __builtin_amdgcn_global_load_lds( \
    (const __attribute__((address_space(1))) void*)(g), \
    (__attribute__((address_space(3))) void*)(l), 16, 0, 0)

// ---------------------------------------------------------------------------
// fp32 -> bf16 conversion of x and the 4 weight matrices.
// ---------------------------------------------------------------------------
#define XN4 786432      // 4096*768/4
#define WN4 147456      // 768*768/4
__global__ __launch_bounds__(256) void convert_kernel(
    const float* __restrict__ x,
    const float* __restrict__ Wq, const float* __restrict__ Wk,
    const float* __restrict__ Wv, const float* __restrict__ Wo,
    __bf16* __restrict__ xb,
    __bf16* __restrict__ Wqb, __bf16* __restrict__ Wkb,
    __bf16* __restrict__ Wvb, __bf16* __restrict__ Wob)
{
    int f = blockIdx.x * 256 + threadIdx.x;
    const float* src; __bf16* dst;
    if (f < XN4)                { src = x;  dst = xb; }
    else if (f < XN4 + WN4)     { src = Wq; dst = Wqb; f -= XN4; }
    else if (f < XN4 + 2*WN4)   { src = Wk; dst = Wkb; f -= XN4 + WN4; }
    else if (f < XN4 + 3*WN4)   { src = Wv; dst = Wvb; f -= XN4 + 2*WN4; }
    else                        { src = Wo; dst = Wob; f -= XN4 + 3*WN4; }
    float4 v = ((const float4*)src)[f];
    v4bf16 b;
    b[0] = (__bf16)v.x; b[1] = (__bf16)v.y;
    b[2] = (__bf16)v.z; b[3] = (__bf16)v.w;
    *(v4bf16*)&dst[(size_t)f * 4] = b;
}

// ---------------------------------------------------------------------------
// QKV MFMA GEMM: C = A @ W^T, A[4096][768] bf16, W[768][768] bf16.
// 128x96 tile, BK=64 (12 k-iters): linear LDS dest + XOR-preswizzled GLOBAL
// source + XOR on read (col8 ^ (row&7)) — rule #21 both-sides swizzle.
// GRID dim3(32, 8, 3), m on x: the 24 blocks sharing one 192 KB A-slice
// co-locate per XCD L2 (R11: part of the −7 us GEMM win).
// z=0: Q (scaled by log2e/sqrt(48)) -> [B,H,S,dk]. z=1: K -> [B,H,S,dk].
// z=2: V -> TRANSPOSED [B,H,dk,S] via b64 stores.
// ---------------------------------------------------------------------------
__global__ __launch_bounds__(256) void qkv_mfma_kernel(
    const __bf16* __restrict__ xb,
    const __bf16* __restrict__ Wqb, const float* __restrict__ bq,
    const __bf16* __restrict__ Wkb, const float* __restrict__ bk,
    const __bf16* __restrict__ Wvb, const float* __restrict__ bv,
    __bf16* __restrict__ Qo, __bf16* __restrict__ Ko, __bf16* __restrict__ Vo)
{
    __shared__ __bf16 As[128 * 64];
    __shared__ __bf16 Bs[128 * 64];

    const int z = blockIdx.z;
    const __bf16* W   = (z == 0) ? Wqb : ((z == 1) ? Wkb : Wvb);
    const float* bias = (z == 0) ? bq  : ((z == 1) ? bk  : bv);
    __bf16* out       = (z == 0) ? Qo  : ((z == 1) ? Ko  : Vo);

    const int m0 = blockIdx.x * 128;         // m on x: A-sharers co-locate
    const int n0 = blockIdx.y * 96;
    const int t  = threadIdx.x;
    const int w    = t >> 6;
    const int lane = t & 63;
    const int low4 = lane & 15;
    const int quad = lane >> 4;
    const int wm = w >> 1, wn = w & 1;
    const int rswz = (low4 & 7) * 8;         // read-side XOR (elems)

    v4f32 acc[4][3];
#pragma unroll
    for (int i = 0; i < 4; ++i)
#pragma unroll
        for (int j = 0; j < 3; ++j)
            acc[i][j] = (v4f32){0.f, 0.f, 0.f, 0.f};

    for (int k0 = 0; k0 < DIM; k0 += 64) {
        // stage 128x64 A and B tiles: 8 GLDS/thread, source-preswizzled
#pragma unroll
        for (int k = 0; k < 4; ++k) {
            const int c = t + k * 256;                 // chunk 0..1023
            const int row = c >> 3, col8 = c & 7;
            GLDS(xb + (size_t)(m0 + row) * DIM + k0 + ((col8 ^ (row & 7)) * 8),
                 &As[c * 8]);
        }
#pragma unroll
        for (int k = 0; k < 4; ++k) {
            const int c = t + k * 256;
            const int row = c >> 3, col8 = c & 7;
            GLDS(W + (size_t)(n0 + row) * DIM + k0 + ((col8 ^ (row & 7)) * 8),
                 &Bs[c * 8]);
        }
        __syncthreads();

#pragma unroll
        for (int kk = 0; kk < 2; ++kk) {
            v8bf16 af[4], bf[3];
            const int cbase = (kk * 32 + quad * 8) ^ rswz;
#pragma unroll
            for (int i = 0; i < 4; ++i)
                af[i] = *(const v8bf16*)&As[(wm * 64 + i * 16 + low4) * 64 + cbase];
#pragma unroll
            for (int j = 0; j < 3; ++j)
                bf[j] = *(const v8bf16*)&Bs[(wn * 48 + j * 16 + low4) * 64 + cbase];
#pragma unroll
            for (int i = 0; i < 4; ++i)
#pragma unroll
                for (int j = 0; j < 3; ++j)
                    acc[i][j] = __builtin_amdgcn_mfma_f32_16x16x32_bf16(af[i], bf[j], acc[i][j], 0, 0, 0);
        }
        __syncthreads();
    }

    // scale = log2(e)/sqrt(48), folded into Q so attention can use exp2
    const float scale = 0.2082351055f;
#pragma unroll
    for (int j = 0; j < 3; ++j) {
        const int e = n0 + wn * 48 + j * 16 + low4;
        const float b = bias[e];
        const int h = e / DKH;
        const int d = e - h * DKH;
        if (z == 2) {
            // V^T: 4 consecutive s per lane -> one b64 store
#pragma unroll
            for (int i = 0; i < 4; ++i) {
                const int m_base = m0 + wm * 64 + i * 16 + quad * 4;
                const int bb = m_base >> 11;
                const int s  = m_base & (SEQ - 1);
                v4bf16 pk;
#pragma unroll
                for (int r = 0; r < 4; ++r) pk[r] = (__bf16)(acc[i][j][r] + b);
                *(v4bf16*)&out[((size_t)(bb * HEADS + h) * DKH + d) * SEQ + s] = pk;
            }
        } else {
#pragma unroll
            for (int i = 0; i < 4; ++i) {
#pragma unroll
                for (int r = 0; r < 4; ++r) {
                    const int m  = m0 + wm * 64 + i * 16 + quad * 4 + r;
                    const int bb = m >> 11;
                    const int s  = m & (SEQ - 1);
                    float v = acc[i][j][r] + b;
                    if (z == 0) v *= scale;
                    out[((size_t)(bb * HEADS + h) * SEQ + s) * DKH + d] = (__bf16)v;
                }
            }
        }
    }
}

// ---------------------------------------------------------------------------
// Output projection: out[m][e] = ctx[m][:] . Wo[e][:] + bo[e], fp32 out.
// 64x96 tile, BK=64, same source-preswizzle scheme as qkv (12 k-iters).
// GRID dim3(64, 8), m on x: CTX-slice sharers co-locate per XCD L2.
// ---------------------------------------------------------------------------
__global__ __launch_bounds__(256) void out_mfma_kernel(
    const __bf16* __restrict__ ctx, const __bf16* __restrict__ Wob,
    const float* __restrict__ bo, float* __restrict__ outp)
{
    __shared__ __bf16 As[64 * 64];
    __shared__ __bf16 Bs[128 * 64];

    const int m0 = blockIdx.x * 64;          // m on x: CTX-sharers co-locate
    const int n0 = blockIdx.y * 96;
    const int t  = threadIdx.x;
    const int w    = t >> 6;
    const int lane = t & 63;
    const int low4 = lane & 15;
    const int quad = lane >> 4;
    const int wm = w >> 1, wn = w & 1;
    const int rswz = (low4 & 7) * 8;

    v4f32 acc[2][3];
#pragma unroll
    for (int i = 0; i < 2; ++i)
#pragma unroll
        for (int j = 0; j < 3; ++j)
            acc[i][j] = (v4f32){0.f, 0.f, 0.f, 0.f};

    for (int k0 = 0; k0 < DIM; k0 += 64) {
#pragma unroll
        for (int k = 0; k < 2; ++k) {
            const int c = t + k * 256;                 // As chunk 0..511
            const int row = c >> 3, col8 = c & 7;
            GLDS(ctx + (size_t)(m0 + row) * DIM + k0 + ((col8 ^ (row & 7)) * 8),
                 &As[c * 8]);
        }
#pragma unroll
        for (int k = 0; k < 4; ++k) {
            const int c = t + k * 256;                 // Bs chunk 0..1023
            const int row = c >> 3, col8 = c & 7;
            GLDS(Wob + (size_t)(n0 + row) * DIM + k0 + ((col8 ^ (row & 7)) * 8),
                 &Bs[c * 8]);
        }
        __syncthreads();

#pragma unroll
        for (int kk = 0; kk < 2; ++kk) {
            v8bf16 af[2], bf[3];
            const int cbase = (kk * 32 + quad * 8) ^ rswz;
#pragma unroll
            for (int i = 0; i < 2; ++i)
                af[i] = *(const v8bf16*)&As[(wm * 32 + i * 16 + low4) * 64 + cbase];
#pragma unroll
            for (int j = 0; j < 3; ++j)
                bf[j] = *(const v8bf16*)&Bs[(wn * 48 + j * 16 + low4) * 64 + cbase];
#pragma unroll
            for (int i = 0; i < 2; ++i)
#pragma unroll
                for (int j = 0; j < 3; ++j)
                    acc[i][j] = __builtin_amdgcn_mfma_f32_16x16x32_bf16(af[i], bf[j], acc[i][j], 0, 0, 0);
        }
        __syncthreads();
    }

#pragma unroll
    for (int j = 0; j < 3; ++j) {
        const int e = n0 + wn * 48 + j * 16 + low4;
        const float b = bo[e];
#pragma unroll
        for (int i = 0; i < 2; ++i) {
#pragma unroll
            for (int r = 0; r < 4; ++r) {
                const int m = m0 + wm * 32 + i * 16 + quad * 4 + r;
                outp[(size_t)m * DIM + e] = acc[i][j][r] + b;
            }
        }
    }
}

// ---------------------------------------------------------------------------
// MFMA flash attention, SPLIT-K x3 (z = key third: 704/704/640 keys),
// no-max softmax (exact: shift-invariant + bounded scores; Q pre-scaled by
// log2e/sqrt(48) -> exp2). 8 waves x 32 queries/wave (measured optimum).
// R12 LESSON (T2 regime gate, m252): XOR-swizzling the LDS tiles removed
// 66% of bank conflicts but COST 8 us — in this 2-barrier lockstep loop the
// conflicts are hidden under the stage/barrier critical path, while the
// per-access swizzle address math is exposed. Linear 72-pitch restored.
// GRID dim3(96, 8): group = bh*3+z on x -> all 8 q-tile blocks sharing one
// K/V third co-locate per XCD (FETCH 55->17 MB).
// Swapped QK^T: S^T = mfma(K,Q) -> packed b64 P-stores, row-major P.
// Waves 0-3 stage K, waves 4-6 stage V (register-prefetch double buffer).
// NO 2nd launch_bounds arg (R1/R8 spill rule). No setprio (R5 regression).
// Outputs UNNORMALIZED O (bf16) + l (fp32); merge kernel divides.
// ---------------------------------------------------------------------------
__global__ __launch_bounds__(512) void attention_kernel(
    const __bf16* __restrict__ Q, const __bf16* __restrict__ K,
    const __bf16* __restrict__ Vt_g, __bf16* __restrict__ Opart,
    float* __restrict__ lbuf)
{
    __shared__ __bf16 PQ[256][72];  // Qs during init, then Ps [query][key]
    __shared__ __bf16 Ks[64][72];   // [key][dk padded 48->64]
    __shared__ __bf16 Vt[48][72];   // [d][key]

    const int grp  = blockIdx.x;            // 0..95: (bh, key-third) group
    const int bh   = grp / 3;
    const int z    = grp - bh * 3;
    const int q0   = blockIdx.y * 256;
    const int kh0  = z * KSPLIT0;                       // key third start
    const int khend = (z == 2) ? SEQ : kh0 + KSPLIT0;
    const int t    = threadIdx.x;
    const int w    = t >> 6;        // 0..7
    const int lane = t & 63;
    const int low4 = lane & 15;
    const int quad = lane >> 4;

    const __bf16* Qbh = Q    + (size_t)bh * SEQ * DKH;
    const __bf16* Kbh = K    + (size_t)bh * SEQ * DKH;
    const __bf16* Vbh = Vt_g + (size_t)bh * SEQ * DKH;  // [d][s]

    // ---- stage Q tile (256 x 48, pre-scaled); zero pad cols 48..63 ----
    {
        const int row = t >> 1;
        const int c0  = (t & 1) * 24;
        const __bf16* src = &Qbh[(size_t)(q0 + row) * DKH + c0];
#pragma unroll
        for (int jj = 0; jj < 6; ++jj)
            *(v4bf16*)&PQ[row][c0 + jj * 4] = *(const v4bf16*)&src[jj * 4];
        v4bf16 zz = {(__bf16)0.f, (__bf16)0.f, (__bf16)0.f, (__bf16)0.f};
        *(v4bf16*)&PQ[row][48 + (t & 1) * 8]     = zz;
        *(v4bf16*)&PQ[row][48 + (t & 1) * 8 + 4] = zz;
        if (t < 256)
            *(v4bf16*)&Ks[t >> 2][48 + (t & 3) * 4] = zz;   // Ks pad cols 48..63
    }
    __syncthreads();

    // Q A-fragments: wave w owns query rows w*32 .. w*32+31 (tiles i=0,1)
    v8bf16 aq[2][2];
#pragma unroll
    for (int i = 0; i < 2; ++i)
#pragma unroll
        for (int ks = 0; ks < 2; ++ks)
            aq[i][ks] = *(const v8bf16*)&PQ[w * 32 + i * 16 + low4][ks * 32 + quad * 8];

    // ones B-fragment for l row-sums
    v8bf16 ones;
#pragma unroll
    for (int jj = 0; jj < 8; ++jj) ones[jj] = (__bf16)1.0f;

    v4f32 lacc[2];
    v4f32 oacc[2][3];
#pragma unroll
    for (int i = 0; i < 2; ++i) {
        lacc[i] = (v4f32){0.f, 0.f, 0.f, 0.f};
#pragma unroll
        for (int dt = 0; dt < 3; ++dt)
            oacc[i][dt] = (v4f32){0.f, 0.f, 0.f, 0.f};
    }

    // staging coords: waves 0-3 -> K (64 rows), waves 4-6 -> V^T (48 rows)
    const int krow = t >> 2;              // K: key row 0..63   (t < 256)
    const int kc0  = (t & 3) * 12;        // K: dk chunk
    const int vrow = (t >> 2) - 64;       // V^T: d row 0..47   (256 <= t < 448)
    const int vc0  = (t & 3) * 16;        // V^T: key chunk

    // ---- prefetch tile 0 into registers ----
    v4bf16 kreg[3];
    v8bf16 vreg0, vreg1;
    if (t < 256) {
        const __bf16* sk = &Kbh[(size_t)(kh0 + krow) * DKH + kc0];
        kreg[0] = *(const v4bf16*)&sk[0];
        kreg[1] = *(const v4bf16*)&sk[4];
        kreg[2] = *(const v4bf16*)&sk[8];
    } else if (t < 448) {
        const __bf16* sv = &Vbh[(size_t)vrow * SEQ + kh0 + vc0];
        vreg0 = *(const v8bf16*)&sv[0];
        vreg1 = *(const v8bf16*)&sv[8];
    }

    for (int k0 = kh0; k0 < khend; k0 += 64) {
        __syncthreads();   // prior LDS reads done (and Q frag reads, iter 0)

        // ---- write prefetched tile to LDS ----
        if (t < 256) {
#pragma unroll
            for (int jj = 0; jj < 3; ++jj)
                *(v4bf16*)&Ks[krow][kc0 + jj * 4] = kreg[jj];
        } else if (t < 448) {
            *(v8bf16*)&Vt[vrow][vc0]     = vreg0;
            *(v8bf16*)&Vt[vrow][vc0 + 8] = vreg1;
        }

        // ---- issue prefetch for next tile (overlaps compute below) ----
        if (k0 + 64 < khend) {
            if (t < 256) {
                const __bf16* sk = &Kbh[(size_t)(k0 + 64 + krow) * DKH + kc0];
                kreg[0] = *(const v4bf16*)&sk[0];
                kreg[1] = *(const v4bf16*)&sk[4];
                kreg[2] = *(const v4bf16*)&sk[8];
            } else if (t < 448) {
                const __bf16* sv = &Vbh[(size_t)vrow * SEQ + (k0 + 64) + vc0];
                vreg0 = *(const v8bf16*)&sv[0];
                vreg1 = *(const v8bf16*)&sv[8];
            }
        }
        __syncthreads();

        // ---- K B-fragments (shared across both query tiles) ----
        v8bf16 bk0[4], bk1[4];
#pragma unroll
        for (int tn = 0; tn < 4; ++tn) {
            bk0[tn] = *(const v8bf16*)&Ks[tn * 16 + low4][quad * 8];
            bk1[tn] = *(const v8bf16*)&Ks[tn * 16 + low4][32 + quad * 8];
        }

        // ---- S^T = K Q^T (swapped), p = exp2(s), packed b64 P-store ----
        // lane: query = low4 (C col), keys = tn*16 + quad*4 + r (C row)
#pragma unroll
        for (int i = 0; i < 2; ++i) {
            v4f32 sacc[4];
#pragma unroll
            for (int tn = 0; tn < 4; ++tn) {
                v4f32 c = {0.f, 0.f, 0.f, 0.f};
                c = __builtin_amdgcn_mfma_f32_16x16x32_bf16(bk0[tn], aq[i][0], c, 0, 0, 0);
                c = __builtin_amdgcn_mfma_f32_16x16x32_bf16(bk1[tn], aq[i][1], c, 0, 0, 0);
                sacc[tn] = c;
            }
#pragma unroll
            for (int tn = 0; tn < 4; ++tn) {
                v4bf16 pk;
#pragma unroll
                for (int r = 0; r < 4; ++r)
                    pk[r] = (__bf16)__builtin_amdgcn_exp2f(sacc[tn][r]);
                *(v4bf16*)&PQ[w * 32 + i * 16 + low4][tn * 16 + quad * 4] = pk;
            }
        }

        // ---- O += P @ V; l += P @ ones ----
        v8bf16 bv0[3], bv1[3];
#pragma unroll
        for (int dt = 0; dt < 3; ++dt) {
            bv0[dt] = *(const v8bf16*)&Vt[dt * 16 + low4][quad * 8];
            bv1[dt] = *(const v8bf16*)&Vt[dt * 16 + low4][32 + quad * 8];
        }
#pragma unroll
        for (int i = 0; i < 2; ++i) {
            v8bf16 ap0 = *(const v8bf16*)&PQ[w * 32 + i * 16 + low4][quad * 8];
            v8bf16 ap1 = *(const v8bf16*)&PQ[w * 32 + i * 16 + low4][32 + quad * 8];
#pragma unroll
            for (int dt = 0; dt < 3; ++dt) {
                oacc[i][dt] = __builtin_amdgcn_mfma_f32_16x16x32_bf16(ap0, bv0[dt], oacc[i][dt], 0, 0, 0);
                oacc[i][dt] = __builtin_amdgcn_mfma_f32_16x16x32_bf16(ap1, bv1[dt], oacc[i][dt], 0, 0, 0);
            }
            lacc[i] = __builtin_amdgcn_mfma_f32_16x16x32_bf16(ap0, ones, lacc[i], 0, 0, 0);
            lacc[i] = __builtin_amdgcn_mfma_f32_16x16x32_bf16(ap1, ones, lacc[i], 0, 0, 0);
        }
    }

    // ---- write unnormalized O partial (bf16) + l (fp32) ----
    const int kh = z;
#pragma unroll
    for (int i = 0; i < 2; ++i) {
#pragma unroll
        for (int r = 0; r < 4; ++r) {
            const int s  = q0 + w * 32 + i * 16 + quad * 4 + r;
            const int qg = bh * SEQ + s;
            __bf16* dst = Opart + (size_t)kh * PART + (size_t)qg * 48;
#pragma unroll
            for (int dt = 0; dt < 3; ++dt)
                dst[dt * 16 + low4] = (__bf16)oacc[i][dt][r];
            if (low4 == 0)
                lbuf[kh * QTOT + qg] = lacc[i][r];
        }
    }
}

// ---------------------------------------------------------------------------
// Merge split-K partials: ctx = sum(Oz) / sum(lz), bf16 out [B,S,768].
// ---------------------------------------------------------------------------
__global__ __launch_bounds__(256) void merge_kernel(
    const __bf16* __restrict__ Opart, const float* __restrict__ lbuf,
    __bf16* __restrict__ ctx)
{
    const int f  = (blockIdx.x * 256 + threadIdx.x) * 8;  // < 32*2048*48
    const int q  = f / 48;          // bh*2048 + s
    const int d0 = f - q * 48;
    v8bf16 a0 = *(const v8bf16*)&Opart[f];
    v8bf16 a1 = *(const v8bf16*)&Opart[(size_t)PART + f];
    v8bf16 a2 = *(const v8bf16*)&Opart[(size_t)2 * PART + f];
    const float inv = 1.0f / (lbuf[q] + lbuf[QTOT + q] + lbuf[2 * QTOT + q]);
    const int bh = q >> 11, s = q & (SEQ - 1);
    const int h = bh & (HEADS - 1), bb = bh >> 4;
    __bf16* dst = ctx + ((size_t)(bb * SEQ + s) * DIM) + h * DKH + d0;
    v8bf16 o;
#pragma unroll
    for (int j = 0; j < 8; ++j)
        o[j] = (__bf16)((((float)a0[j] + (float)a1[j]) + (float)a2[j]) * inv);
    *(v8bf16*)dst = o;
}

// ---------------------------------------------------------------------------
extern "C" void kernel_launch(void* const* d_in, const int* in_sizes, int n_in,
                              void* d_out, int out_size, void* d_ws, size_t ws_size,
                              hipStream_t stream) {
    const float* x  = (const float*)d_in[0];
    const float* Wq = (const float*)d_in[1];
    const float* bq = (const float*)d_in[2];
    const float* Wk = (const float*)d_in[3];
    const float* bk = (const float*)d_in[4];
    const float* Wv = (const float*)d_in[5];
    const float* bv = (const float*)d_in[6];
    const float* Wo = (const float*)d_in[7];
    const float* bo = (const float*)d_in[8];
    float* out = (float*)d_out;

    char* ws = (char*)d_ws;
    const size_t XB  = (size_t)M_TOT * DIM * 2;    // 6291456
    const size_t WBP = (size_t)800 * DIM * 2;      // 1228800 (768 rows + 32 pad)

    // Layout (peak ~46 MB). Opart/lbuf overlay the xb + Wq/Wk/Wv region,
    // which is dead once the QKV GEMM has run (kernels are stream-ordered).
    __bf16* Wob = (__bf16*)(ws);                       // lives until out_mfma
    __bf16* CTX = (__bf16*)(ws + WBP);
    __bf16* Qb  = (__bf16*)(ws + WBP + XB);
    __bf16* Kb  = (__bf16*)(ws + WBP + 2 * XB);
    __bf16* Vb  = (__bf16*)(ws + WBP + 3 * XB);        // [B,H,dk,S]
    __bf16* xb  = (__bf16*)(ws + WBP + 4 * XB);
    __bf16* Wqb = (__bf16*)(ws + WBP + 5 * XB);
    __bf16* Wkb = (__bf16*)(ws + WBP + 5 * XB + WBP);
    __bf16* Wvb = (__bf16*)(ws + WBP + 5 * XB + 2 * WBP);
    __bf16* Opart = (__bf16*)(ws + WBP + 4 * XB);                 // 3*PART bf16
    float*  lbuf  = (float*)(ws + WBP + 4 * XB + (size_t)KSPL * PART * 2);

    // 0) fp32 -> bf16 conversion of x and weights
    convert_kernel<<<dim3((XN4 + 4 * WN4) / 256), 256, 0, stream>>>(
        x, Wq, Wk, Wv, Wo, xb, Wqb, Wkb, Wvb, Wob);

    // 1) QKV projections (MFMA): grid (32 m, 8 n, 3 z) = 768 blocks,
    //    m on x so the 24 A-slice sharers co-locate per XCD L2
    qkv_mfma_kernel<<<dim3(32, 8, 3), 256, 0, stream>>>(
        xb, Wqb, bq, Wkb, bk, Wvb, bv, Qb, Kb, Vb);

    // 2) attention split-K: grid (96 groups = bh*3+z, 8 q-tiles) = 768 blocks
    //    = exactly 3 blocks/CU; XCD-aware: K/V sharers co-located per XCD L2
    attention_kernel<<<dim3(96, 8), 512, 0, stream>>>(Qb, Kb, Vb, Opart, lbuf);

    // 2b) merge partials: 32*2048*48/8/256 = 1536 blocks
    merge_kernel<<<dim3(1536), 256, 0, stream>>>(Opart, lbuf, CTX);

    // 3) output projection (MFMA): grid (64 m, 8 n) = 512 blocks,
    //    m on x so the 8 CTX-slice sharers co-locate per XCD L2
    out_mfma_kernel<<<dim3(64, 8), 256, 0, stream>>>(CTX, Wob, bo, out);
}